// Round 5
// baseline (197.316 us; speedup 1.0000x reference)
//
#include <hip/hip_runtime.h>

// Head: single-head causal attention. B=4, T=2048, D=1024, H=64. fp32 in/out.
// R5 = R4 with the ws-layout overlap fixed (Opart is 33,554,432 B; mpart had
// been placed 128 B early, so Opart id=16383 clobbered mpart[0..31] -> exp of
// poison -> absmax 2e33).
//  - qkv: canonical LDS-staged GEMM (contiguous 512B staging bursts, bf16 LDS,
//    double-buffered) -- kills the 4KB-strided A-frag reads that pinned R2/R3.
//  - attn: 1 K-tile per wave (plain softmax), bf16 O-partials + fp32 m/l.
//
// ws layout (bytes):
//   [0,        393216)   Wt    bf16 [192][1024]
//   [393216,  1441792)   q     bf16 [8192][64]
//   [1441792, 2490368)   k     bf16 [8192][64]
//   [2490368, 3538944)   vT    bf16 [4][64][2048]
//   [3538944, 37093376)  Opart bf16 [16384][16][64]  (id = b*4096+qt*32+kc)
//   [37093376,38141952)  mpart fp32 [16384][16]
//   [38141952,39190528)  lpart fp32 [16384][16]

typedef __attribute__((ext_vector_type(8))) __bf16 bf16x8;
typedef __attribute__((ext_vector_type(4))) float floatx4;

union BF8 {
    bf16x8 v;
    unsigned short s[8];
    uint4 u;
};
union BF4 {
    unsigned short s[4];
    unsigned long long ull;
};

__device__ inline unsigned short f2bf(float f) {
    unsigned int u = __float_as_uint(f);
    unsigned int r = (u + 0x7fffu + ((u >> 16) & 1u)) >> 16;
    return (unsigned short)r;
}
__device__ inline float bf2f(unsigned short s) {
    unsigned int u = ((unsigned int)s) << 16;
    return __uint_as_float(u);
}

// ---------------------------------------------------------------------------
// Kernel 0: Wt[n][kk] = bf16(W_{n/64}[kk][n%64])
// ---------------------------------------------------------------------------
__global__ __launch_bounds__(256) void wt_kernel(const float* __restrict__ Wq,
                                                 const float* __restrict__ Wk,
                                                 const float* __restrict__ Wv,
                                                 unsigned short* __restrict__ wt) {
    int idx = blockIdx.x * 256 + threadIdx.x;
    int kk = idx / 192;
    int n = idx - kk * 192;
    int sel = n >> 6;
    int h = n & 63;
    const float* W = (sel == 0) ? Wq : (sel == 1) ? Wk : Wv;
    wt[(size_t)n * 1024 + kk] = f2bf(W[(size_t)kk * 64 + h]);
}

// ---------------------------------------------------------------------------
// Kernel 1: QKV projection, LDS-staged. Grid 256 = 128 M-tiles(64 rows) x 2
// N-halves(96 cols). Block 256 thr / 4 waves; wave = 16 rows x 96 cols.
// K-chunks of 128: stage x fp32->bf16 into padded LDS [64][136] (double-
// buffered); staging loads are contiguous 512-B row segments. A-frags via
// ds_read_b128 (2-way bank alias = free); B-frags from L1-resident wt.
// v output transposed through LDS -> full-line vT stores.
// ---------------------------------------------------------------------------
__global__ __launch_bounds__(256) void qkv_kernel(const float* __restrict__ x,
                                                  const unsigned short* __restrict__ wt,
                                                  unsigned short* __restrict__ qo,
                                                  unsigned short* __restrict__ ko,
                                                  unsigned short* __restrict__ vo) {
    __shared__ __align__(16) unsigned short lx[2][64 * 136];
    __shared__ __align__(16) unsigned short vtile[64 * 72];
    const int tid = threadIdx.x;
    const int w = tid >> 6;
    const int lane = tid & 63;
    const int quad = lane >> 4;
    const int l16 = lane & 15;
    const int m0 = (blockIdx.x >> 1) * 64;
    const int half = blockIdx.x & 1;

    const int srow = tid >> 5;  // 0..7
    const int scol = tid & 31;  // float4 index within 128-col chunk

    float4 ld[8];
    const float* xbase = x + (size_t)m0 * 1024 + (size_t)srow * 1024 + scol * 4;

#define LOAD_CHUNK(c)                                                  \
    {                                                                  \
        const float* p_ = xbase + (c) * 128;                           \
        _Pragma("unroll") for (int i_ = 0; i_ < 8; ++i_)               \
            ld[i_] = *(const float4*)(p_ + (size_t)i_ * 8 * 1024);     \
    }
#define WRITE_CHUNK(buf)                                               \
    {                                                                  \
        unsigned short* p_ = &lx[buf][0] + srow * 136 + scol * 4;      \
        _Pragma("unroll") for (int i_ = 0; i_ < 8; ++i_) {             \
            BF4 b_;                                                    \
            b_.s[0] = f2bf(ld[i_].x); b_.s[1] = f2bf(ld[i_].y);        \
            b_.s[2] = f2bf(ld[i_].z); b_.s[3] = f2bf(ld[i_].w);        \
            *(unsigned long long*)(p_ + i_ * 8 * 136) = b_.ull;        \
        }                                                              \
    }

    floatx4 acc[6];
#pragma unroll
    for (int i = 0; i < 6; ++i) acc[i] = (floatx4)(0.0f);

    LOAD_CHUNK(0);
    WRITE_CHUNK(0);
    __syncthreads();

    for (int c = 0; c < 8; ++c) {
        if (c < 7) LOAD_CHUNK(c + 1);
        const unsigned short* lp = &lx[c & 1][0] + (w * 16 + l16) * 136 + quad * 8;
        const unsigned short* wp = wt + (size_t)(half * 96 + l16) * 1024 + c * 128 + quad * 8;
#pragma unroll
        for (int kst = 0; kst < 4; ++kst) {
            BF8 a;
            a.u = *(const uint4*)(lp + kst * 32);
#pragma unroll
            for (int nt = 0; nt < 6; ++nt) {
                BF8 b;
                b.u = *(const uint4*)(wp + (size_t)nt * 16 * 1024 + kst * 32);
                acc[nt] = __builtin_amdgcn_mfma_f32_16x16x32_bf16(a.v, b.v, acc[nt], 0, 0, 0);
            }
        }
        if (c < 7) WRITE_CHUNK((c + 1) & 1);
        __syncthreads();
    }

    const int trow = m0 + w * 16 + quad * 4;
    if (half == 0) {
        // n-tiles 0..3 -> q h=nt*16+l16 ; 4,5 -> k h=(nt-4)*16+l16
#pragma unroll
        for (int nt = 0; nt < 4; ++nt)
#pragma unroll
            for (int r = 0; r < 4; ++r)
                qo[(size_t)(trow + r) * 64 + nt * 16 + l16] = f2bf(acc[nt][r]);
#pragma unroll
        for (int nt = 4; nt < 6; ++nt)
#pragma unroll
            for (int r = 0; r < 4; ++r)
                ko[(size_t)(trow + r) * 64 + (nt - 4) * 16 + l16] = f2bf(acc[nt][r]);
    } else {
        // n-tiles 0,1 -> k h=32+nt*16+l16 ; 2..5 -> v h=(nt-2)*16+l16 (via LDS)
#pragma unroll
        for (int nt = 0; nt < 2; ++nt)
#pragma unroll
            for (int r = 0; r < 4; ++r)
                ko[(size_t)(trow + r) * 64 + 32 + nt * 16 + l16] = f2bf(acc[nt][r]);
        const int tloc = w * 16 + quad * 4;
#pragma unroll
        for (int nt = 2; nt < 6; ++nt) {
            BF4 pk;
#pragma unroll
            for (int r = 0; r < 4; ++r) pk.s[r] = f2bf(acc[nt][r]);
            *(unsigned long long*)&vtile[((nt - 2) * 16 + l16) * 72 + tloc] = pk.ull;
        }
        __syncthreads();
        const int b = m0 >> 11;
        const int h = tid >> 2;
        const int seg = tid & 3;
        uint4 v0 = *(const uint4*)&vtile[h * 72 + seg * 16];
        uint4 v1 = *(const uint4*)&vtile[h * 72 + seg * 16 + 8];
        unsigned short* dst = vo + (size_t)(b * 64 + h) * 2048 + (m0 & 2047) + seg * 16;
        *(uint4*)dst = v0;
        *(uint4*)(dst + 8) = v1;
    }
#undef LOAD_CHUNK
#undef WRITE_CHUNK
}

// ---------------------------------------------------------------------------
// Kernel 2: flash pass A, ONE 64-key tile per wave. id in [0,16384):
// b=id>>12, qt=(id>>5)&127, kc=id&31. Active iff kc <= qt>>2 (8384 waves).
// Plain softmax (single tile: no online rescale). Partials: O bf16, m/l fp32.
// ---------------------------------------------------------------------------
__global__ __launch_bounds__(256) void attn_partial(const unsigned short* __restrict__ qi,
                                                    const unsigned short* __restrict__ ki,
                                                    const unsigned short* __restrict__ vT,
                                                    unsigned short* __restrict__ Opart,
                                                    float* __restrict__ mpart,
                                                    float* __restrict__ lpart) {
    __shared__ __align__(16) unsigned short lds_p[4 * 16 * 72];
    const int tid = threadIdx.x;
    const int w = tid >> 6;
    const int lane = tid & 63;
    const int quad = lane >> 4;
    const int l16 = lane & 15;
    const int id = blockIdx.x * 4 + w;
    const int b = id >> 12;
    const int qt = (id >> 5) & 127;
    const int kc = id & 31;
    if (kc > (qt >> 2)) return;
    const int r0 = qt * 16;
    const int j0 = kc * 64;

    BF8 aq[2];
    {
        const unsigned short* qp = qi + (size_t)(b * 2048 + r0 + l16) * 64 + quad * 8;
        aq[0].u = *(const uint4*)(qp);
        aq[1].u = *(const uint4*)(qp + 32);
    }

    floatx4 s[4];
#pragma unroll
    for (int nt = 0; nt < 4; ++nt) s[nt] = (floatx4)(0.0f);
#pragma unroll
    for (int kst = 0; kst < 2; ++kst) {
#pragma unroll
        for (int nt = 0; nt < 4; ++nt) {
            BF8 bk;
            bk.u = *(const uint4*)(ki + (size_t)(b * 2048 + j0 + nt * 16 + l16) * 64 +
                                   kst * 32 + quad * 8);
            s[nt] = __builtin_amdgcn_mfma_f32_16x16x32_bf16(aq[kst].v, bk.v, s[nt], 0, 0, 0);
        }
    }

    float sv[4][4];
    const bool masked = (j0 + 63 > r0);
#pragma unroll
    for (int nt = 0; nt < 4; ++nt)
#pragma unroll
        for (int r = 0; r < 4; ++r) {
            float val = s[nt][r] * 0.125f;
            if (masked) {
                int key = j0 + nt * 16 + l16;
                int qr = r0 + quad * 4 + r;
                if (key > qr) val = -3.0e38f;
            }
            sv[nt][r] = val;
        }

    float m_i[4], l_i[4];
#pragma unroll
    for (int r = 0; r < 4; ++r) {
        float mx = fmaxf(fmaxf(sv[0][r], sv[1][r]), fmaxf(sv[2][r], sv[3][r]));
        mx = fmaxf(mx, __shfl_xor(mx, 1));
        mx = fmaxf(mx, __shfl_xor(mx, 2));
        mx = fmaxf(mx, __shfl_xor(mx, 4));
        mx = fmaxf(mx, __shfl_xor(mx, 8));
        m_i[r] = mx;
    }
    float rs[4] = {0.f, 0.f, 0.f, 0.f};
#pragma unroll
    for (int nt = 0; nt < 4; ++nt)
#pragma unroll
        for (int r = 0; r < 4; ++r) {
            float p = __expf(sv[nt][r] - m_i[r]);
            sv[nt][r] = p;
            rs[r] += p;
        }
#pragma unroll
    for (int r = 0; r < 4; ++r) {
        float t2 = rs[r];
        t2 += __shfl_xor(t2, 1);
        t2 += __shfl_xor(t2, 2);
        t2 += __shfl_xor(t2, 4);
        t2 += __shfl_xor(t2, 8);
        l_i[r] = t2;
    }

    unsigned short* myp = lds_p + w * (16 * 72);
#pragma unroll
    for (int nt = 0; nt < 4; ++nt)
#pragma unroll
        for (int r = 0; r < 4; ++r)
            myp[(quad * 4 + r) * 72 + nt * 16 + l16] = f2bf(sv[nt][r]);

    floatx4 oacc[4];
#pragma unroll
    for (int nt = 0; nt < 4; ++nt) oacc[nt] = (floatx4)(0.0f);
#pragma unroll
    for (int kst = 0; kst < 2; ++kst) {
        BF8 ap;
        ap.u = *(const uint4*)(myp + l16 * 72 + kst * 32 + quad * 8);
#pragma unroll
        for (int nt = 0; nt < 4; ++nt) {
            BF8 bv;
            bv.u = *(const uint4*)(vT + (size_t)(b * 64 + nt * 16 + l16) * 2048 + j0 +
                                   kst * 32 + quad * 8);
            oacc[nt] = __builtin_amdgcn_mfma_f32_16x16x32_bf16(ap.v, bv.v, oacc[nt], 0, 0, 0);
        }
    }

    const size_t ob = (size_t)id * 1024;
#pragma unroll
    for (int nt = 0; nt < 4; ++nt)
#pragma unroll
        for (int r = 0; r < 4; ++r)
            Opart[ob + (quad * 4 + r) * 64 + nt * 16 + l16] = f2bf(oacc[nt][r]);
    if (l16 == 0) {
#pragma unroll
        for (int r = 0; r < 4; ++r) {
            mpart[id * 16 + quad * 4 + r] = m_i[r];
            lpart[id * 16 + quad * 4 + r] = l_i[r];
        }
    }
}

// ---------------------------------------------------------------------------
// Kernel 3: merge. Block per q-tile (512 blocks x 256). Wave w: rows
// w*4..w*4+3; lane = col. nc = (qt>>2)+1 partials (<=32).
// ---------------------------------------------------------------------------
__global__ __launch_bounds__(256) void attn_merge(const unsigned short* __restrict__ Opart,
                                                  const float* __restrict__ mpart,
                                                  const float* __restrict__ lpart,
                                                  float* __restrict__ out) {
    const int tid = threadIdx.x;
    const int w = tid >> 6;
    const int lane = tid & 63;
    const int b = blockIdx.x >> 7;
    const int qt = blockIdx.x & 127;
    const int nc = (qt >> 2) + 1;
    const int base_id = b * 4096 + qt * 32;

#pragma unroll
    for (int rr = 0; rr < 4; ++rr) {
        const int r = w * 4 + rr;
        float M = -3.0e38f;
        for (int c = 0; c < nc; ++c) M = fmaxf(M, mpart[(base_id + c) * 16 + r]);
        float L = 0.0f, O = 0.0f;
        for (int c = 0; c < nc; ++c) {
            float e = __expf(mpart[(base_id + c) * 16 + r] - M);
            L += e * lpart[(base_id + c) * 16 + r];
            O += e * bf2f(Opart[(size_t)(base_id + c) * 1024 + r * 64 + lane]);
        }
        out[(size_t)(b * 2048 + qt * 16 + r) * 64 + lane] = O / L;
    }
}

extern "C" void kernel_launch(void* const* d_in, const int* in_sizes, int n_in,
                              void* d_out, int out_size, void* d_ws, size_t ws_size,
                              hipStream_t stream) {
    const float* x = (const float*)d_in[0];
    const float* Wq = (const float*)d_in[1];
    const float* Wk = (const float*)d_in[2];
    const float* Wv = (const float*)d_in[3];
    float* out = (float*)d_out;

    char* ws = (char*)d_ws;
    unsigned short* wt = (unsigned short*)(ws);
    unsigned short* q = (unsigned short*)(ws + 393216);
    unsigned short* k = (unsigned short*)(ws + 1441792);
    unsigned short* vT = (unsigned short*)(ws + 2490368);
    unsigned short* Opart = (unsigned short*)(ws + 3538944);
    float* mpart = (float*)(ws + 37093376ull);
    float* lpart = (float*)(ws + 38141952ull);

    hipLaunchKernelGGL(wt_kernel, dim3(768), dim3(256), 0, stream, Wq, Wk, Wv, wt);
    hipLaunchKernelGGL(qkv_kernel, dim3(256), dim3(256), 0, stream, x, wt, q, k, vT);
    hipLaunchKernelGGL(attn_partial, dim3(4096), dim3(256), 0, stream, q, k, vT, Opart, mpart, lpart);
    hipLaunchKernelGGL(attn_merge, dim3(512), dim3(256), 0, stream, Opart, mpart, lpart, out);
}

// Round 6
// 158.902 us; speedup vs baseline: 1.2417x; 1.2417x over previous
//
#include <hip/hip_runtime.h>

// Head: single-head causal attention. B=4, T=2048, D=1024, H=64. fp32 in/out.
// R6: (a) merge rewritten flat (1 thread per output element, 2048 blocks,
// 8 waves/SIMD) -- R5 merge was 59us: 4rows x 64 serial dependent-load
// iterations per wave at 2 waves/SIMD. (b) qkv: 512-thr blocks, wave pairs
// split the K-chunk (kst 0-1 vs 2-3) + LDS reduce -> 2 waves/SIMD, half the
// serial MFMA chain. attn_partial unchanged.
//
// ws layout (bytes):
//   [0,        393216)   Wt    bf16 [192][1024]
//   [393216,  1441792)   q     bf16 [8192][64]
//   [1441792, 2490368)   k     bf16 [8192][64]
//   [2490368, 3538944)   vT    bf16 [4][64][2048]
//   [3538944, 37093376)  Opart bf16 [16384][16][64]  (id = b*4096+qt*32+kc)
//   [37093376,38141952)  mpart fp32 [16384][16]
//   [38141952,39190528)  lpart fp32 [16384][16]

typedef __attribute__((ext_vector_type(8))) __bf16 bf16x8;
typedef __attribute__((ext_vector_type(4))) float floatx4;

union BF8 {
    bf16x8 v;
    unsigned short s[8];
    uint4 u;
};
union BF4 {
    unsigned short s[4];
    unsigned long long ull;
};

__device__ inline unsigned short f2bf(float f) {
    unsigned int u = __float_as_uint(f);
    unsigned int r = (u + 0x7fffu + ((u >> 16) & 1u)) >> 16;
    return (unsigned short)r;
}
__device__ inline float bf2f(unsigned short s) {
    unsigned int u = ((unsigned int)s) << 16;
    return __uint_as_float(u);
}

// ---------------------------------------------------------------------------
// Kernel 0: Wt[n][kk] = bf16(W_{n/64}[kk][n%64])
// ---------------------------------------------------------------------------
__global__ __launch_bounds__(256) void wt_kernel(const float* __restrict__ Wq,
                                                 const float* __restrict__ Wk,
                                                 const float* __restrict__ Wv,
                                                 unsigned short* __restrict__ wt) {
    int idx = blockIdx.x * 256 + threadIdx.x;
    int kk = idx / 192;
    int n = idx - kk * 192;
    int sel = n >> 6;
    int h = n & 63;
    const float* W = (sel == 0) ? Wq : (sel == 1) ? Wk : Wv;
    wt[(size_t)n * 1024 + kk] = f2bf(W[(size_t)kk * 64 + h]);
}

// ---------------------------------------------------------------------------
// Kernel 1: QKV projection, LDS-staged, 512 thr / 8 waves. Grid 256 =
// 128 M-tiles(64 rows) x 2 N-halves(96 cols). Wave pair (w, w+4): same
// 16 rows x 96 cols, w<4 does kst 0-1, w>=4 does kst 2-3 of each 128-chunk;
// partial accs summed through LDS at the end (waves 0-3 hold the result and
// run the epilogue). Staging: contiguous 512-B bursts, fp32->bf16, padded
// LDS [64][136], double-buffered.
// ---------------------------------------------------------------------------
__global__ __launch_bounds__(512) void qkv_kernel(const float* __restrict__ x,
                                                  const unsigned short* __restrict__ wt,
                                                  unsigned short* __restrict__ qo,
                                                  unsigned short* __restrict__ ko,
                                                  unsigned short* __restrict__ vo) {
    __shared__ __align__(16) unsigned short lx[2][64 * 136];
    __shared__ __align__(16) unsigned short vtile[64 * 72];
    const int tid = threadIdx.x;
    const int w = tid >> 6;       // 0..7
    const int wl = w & 3;         // logical wave (row-group owner)
    const int lane = tid & 63;
    const int quad = lane >> 4;
    const int l16 = lane & 15;
    const int m0 = (blockIdx.x >> 1) * 64;
    const int half = blockIdx.x & 1;

    const int srow = tid >> 5;  // 0..15
    const int scol = tid & 31;  // float4 index within 128-col chunk

    float4 ld[4];
    const float* xbase = x + (size_t)(m0 + srow) * 1024 + scol * 4;

#define LOAD_CHUNK(c)                                                  \
    {                                                                  \
        const float* p_ = xbase + (c) * 128;                           \
        _Pragma("unroll") for (int i_ = 0; i_ < 4; ++i_)               \
            ld[i_] = *(const float4*)(p_ + (size_t)i_ * 16 * 1024);    \
    }
#define WRITE_CHUNK(buf)                                               \
    {                                                                  \
        unsigned short* p_ = &lx[buf][0] + srow * 136 + scol * 4;      \
        _Pragma("unroll") for (int i_ = 0; i_ < 4; ++i_) {             \
            BF4 b_;                                                    \
            b_.s[0] = f2bf(ld[i_].x); b_.s[1] = f2bf(ld[i_].y);        \
            b_.s[2] = f2bf(ld[i_].z); b_.s[3] = f2bf(ld[i_].w);        \
            *(unsigned long long*)(p_ + i_ * 16 * 136) = b_.ull;       \
        }                                                              \
    }

    floatx4 acc[6];
#pragma unroll
    for (int i = 0; i < 6; ++i) acc[i] = (floatx4)(0.0f);

    const int kst0 = (w >> 2) * 2;  // 0 or 2

    LOAD_CHUNK(0);
    WRITE_CHUNK(0);
    __syncthreads();

    for (int c = 0; c < 8; ++c) {
        if (c < 7) LOAD_CHUNK(c + 1);
        const unsigned short* lp = &lx[c & 1][0] + (wl * 16 + l16) * 136 + quad * 8;
        const unsigned short* wp = wt + (size_t)(half * 96 + l16) * 1024 + c * 128 + quad * 8;
#pragma unroll
        for (int k2 = 0; k2 < 2; ++k2) {
            const int kst = kst0 + k2;
            BF8 a;
            a.u = *(const uint4*)(lp + kst * 32);
#pragma unroll
            for (int nt = 0; nt < 6; ++nt) {
                BF8 b;
                b.u = *(const uint4*)(wp + (size_t)nt * 16 * 1024 + kst * 32);
                acc[nt] = __builtin_amdgcn_mfma_f32_16x16x32_bf16(a.v, b.v, acc[nt], 0, 0, 0);
            }
        }
        if (c < 7) WRITE_CHUNK((c + 1) & 1);
        __syncthreads();
    }

    // cross-wave reduce: waves 4-7 dump accs into LDS (reuse lx; 24576 B),
    // waves 0-3 add them.
    float* red = (float*)&lx[0][0];
    if (w >= 4) {
#pragma unroll
        for (int nt = 0; nt < 6; ++nt)
#pragma unroll
            for (int r = 0; r < 4; ++r)
                red[((wl * 6 + nt) * 4 + r) * 64 + lane] = acc[nt][r];
    }
    __syncthreads();
    if (w < 4) {
#pragma unroll
        for (int nt = 0; nt < 6; ++nt)
#pragma unroll
            for (int r = 0; r < 4; ++r)
                acc[nt][r] += red[((wl * 6 + nt) * 4 + r) * 64 + lane];
    }

    const int trow = m0 + wl * 16 + quad * 4;
    if (half == 0) {
        if (w < 4) {
            // n-tiles 0..3 -> q h=nt*16+l16 ; 4,5 -> k h=(nt-4)*16+l16
#pragma unroll
            for (int nt = 0; nt < 4; ++nt)
#pragma unroll
                for (int r = 0; r < 4; ++r)
                    qo[(size_t)(trow + r) * 64 + nt * 16 + l16] = f2bf(acc[nt][r]);
#pragma unroll
            for (int nt = 4; nt < 6; ++nt)
#pragma unroll
                for (int r = 0; r < 4; ++r)
                    ko[(size_t)(trow + r) * 64 + (nt - 4) * 16 + l16] = f2bf(acc[nt][r]);
        }
    } else {
        if (w < 4) {
            // n-tiles 0,1 -> k h=32+nt*16+l16 ; 2..5 -> v h=(nt-2)*16+l16
#pragma unroll
            for (int nt = 0; nt < 2; ++nt)
#pragma unroll
                for (int r = 0; r < 4; ++r)
                    ko[(size_t)(trow + r) * 64 + 32 + nt * 16 + l16] = f2bf(acc[nt][r]);
            const int tloc = wl * 16 + quad * 4;
#pragma unroll
            for (int nt = 2; nt < 6; ++nt) {
                BF4 pk;
#pragma unroll
                for (int r = 0; r < 4; ++r) pk.s[r] = f2bf(acc[nt][r]);
                *(unsigned long long*)&vtile[((nt - 2) * 16 + l16) * 72 + tloc] = pk.ull;
            }
        }
        __syncthreads();
        if (tid < 256) {
            const int b = m0 >> 11;
            const int h = tid >> 2;
            const int seg = tid & 3;
            uint4 v0 = *(const uint4*)&vtile[h * 72 + seg * 16];
            uint4 v1 = *(const uint4*)&vtile[h * 72 + seg * 16 + 8];
            unsigned short* dst = vo + (size_t)(b * 64 + h) * 2048 + (m0 & 2047) + seg * 16;
            *(uint4*)dst = v0;
            *(uint4*)(dst + 8) = v1;
        }
    }
#undef LOAD_CHUNK
#undef WRITE_CHUNK
}

// ---------------------------------------------------------------------------
// Kernel 2: flash pass A, ONE 64-key tile per wave. id in [0,16384):
// b=id>>12, qt=(id>>5)&127, kc=id&31. Active iff kc <= qt>>2 (8384 waves).
// Plain softmax (single tile). Partials: O bf16, m/l fp32. (unchanged R5)
// ---------------------------------------------------------------------------
__global__ __launch_bounds__(256) void attn_partial(const unsigned short* __restrict__ qi,
                                                    const unsigned short* __restrict__ ki,
                                                    const unsigned short* __restrict__ vT,
                                                    unsigned short* __restrict__ Opart,
                                                    float* __restrict__ mpart,
                                                    float* __restrict__ lpart) {
    __shared__ __align__(16) unsigned short lds_p[4 * 16 * 72];
    const int tid = threadIdx.x;
    const int w = tid >> 6;
    const int lane = tid & 63;
    const int quad = lane >> 4;
    const int l16 = lane & 15;
    const int id = blockIdx.x * 4 + w;
    const int b = id >> 12;
    const int qt = (id >> 5) & 127;
    const int kc = id & 31;
    if (kc > (qt >> 2)) return;
    const int r0 = qt * 16;
    const int j0 = kc * 64;

    BF8 aq[2];
    {
        const unsigned short* qp = qi + (size_t)(b * 2048 + r0 + l16) * 64 + quad * 8;
        aq[0].u = *(const uint4*)(qp);
        aq[1].u = *(const uint4*)(qp + 32);
    }

    floatx4 s[4];
#pragma unroll
    for (int nt = 0; nt < 4; ++nt) s[nt] = (floatx4)(0.0f);
#pragma unroll
    for (int kst = 0; kst < 2; ++kst) {
#pragma unroll
        for (int nt = 0; nt < 4; ++nt) {
            BF8 bk;
            bk.u = *(const uint4*)(ki + (size_t)(b * 2048 + j0 + nt * 16 + l16) * 64 +
                                   kst * 32 + quad * 8);
            s[nt] = __builtin_amdgcn_mfma_f32_16x16x32_bf16(aq[kst].v, bk.v, s[nt], 0, 0, 0);
        }
    }

    float sv[4][4];
    const bool masked = (j0 + 63 > r0);
#pragma unroll
    for (int nt = 0; nt < 4; ++nt)
#pragma unroll
        for (int r = 0; r < 4; ++r) {
            float val = s[nt][r] * 0.125f;
            if (masked) {
                int key = j0 + nt * 16 + l16;
                int qr = r0 + quad * 4 + r;
                if (key > qr) val = -3.0e38f;
            }
            sv[nt][r] = val;
        }

    float m_i[4], l_i[4];
#pragma unroll
    for (int r = 0; r < 4; ++r) {
        float mx = fmaxf(fmaxf(sv[0][r], sv[1][r]), fmaxf(sv[2][r], sv[3][r]));
        mx = fmaxf(mx, __shfl_xor(mx, 1));
        mx = fmaxf(mx, __shfl_xor(mx, 2));
        mx = fmaxf(mx, __shfl_xor(mx, 4));
        mx = fmaxf(mx, __shfl_xor(mx, 8));
        m_i[r] = mx;
    }
    float rs[4] = {0.f, 0.f, 0.f, 0.f};
#pragma unroll
    for (int nt = 0; nt < 4; ++nt)
#pragma unroll
        for (int r = 0; r < 4; ++r) {
            float p = __expf(sv[nt][r] - m_i[r]);
            sv[nt][r] = p;
            rs[r] += p;
        }
#pragma unroll
    for (int r = 0; r < 4; ++r) {
        float t2 = rs[r];
        t2 += __shfl_xor(t2, 1);
        t2 += __shfl_xor(t2, 2);
        t2 += __shfl_xor(t2, 4);
        t2 += __shfl_xor(t2, 8);
        l_i[r] = t2;
    }

    unsigned short* myp = lds_p + w * (16 * 72);
#pragma unroll
    for (int nt = 0; nt < 4; ++nt)
#pragma unroll
        for (int r = 0; r < 4; ++r)
            myp[(quad * 4 + r) * 72 + nt * 16 + l16] = f2bf(sv[nt][r]);

    floatx4 oacc[4];
#pragma unroll
    for (int nt = 0; nt < 4; ++nt) oacc[nt] = (floatx4)(0.0f);
#pragma unroll
    for (int kst = 0; kst < 2; ++kst) {
        BF8 ap;
        ap.u = *(const uint4*)(myp + l16 * 72 + kst * 32 + quad * 8);
#pragma unroll
        for (int nt = 0; nt < 4; ++nt) {
            BF8 bv;
            bv.u = *(const uint4*)(vT + (size_t)(b * 64 + nt * 16 + l16) * 2048 + j0 +
                                   kst * 32 + quad * 8);
            oacc[nt] = __builtin_amdgcn_mfma_f32_16x16x32_bf16(ap.v, bv.v, oacc[nt], 0, 0, 0);
        }
    }

    const size_t ob = (size_t)id * 1024;
#pragma unroll
    for (int nt = 0; nt < 4; ++nt)
#pragma unroll
        for (int r = 0; r < 4; ++r)
            Opart[ob + (quad * 4 + r) * 64 + nt * 16 + l16] = f2bf(oacc[nt][r]);
    if (l16 == 0) {
#pragma unroll
        for (int r = 0; r < 4; ++r) {
            mpart[id * 16 + quad * 4 + r] = m_i[r];
            lpart[id * 16 + quad * 4 + r] = l_i[r];
        }
    }
}

// ---------------------------------------------------------------------------
// Kernel 3: merge, flat. One thread per output element (524288), 2048 blocks.
// e: col=e&63, row16=(e>>6)&15, qt=(e>>10)&127, b=e>>17. Wave = 64 cols of
// one row -> Opart 128B coalesced, mpart/lpart wave-uniform broadcasts.
// 8 blocks/CU -> latency hidden by TLP (was: 2 waves/SIMD + 256 serial
// dependent loads per wave = 59us).
// ---------------------------------------------------------------------------
__global__ __launch_bounds__(256) void attn_merge(const unsigned short* __restrict__ Opart,
                                                  const float* __restrict__ mpart,
                                                  const float* __restrict__ lpart,
                                                  float* __restrict__ out) {
    const int e = blockIdx.x * 256 + threadIdx.x;
    const int col = e & 63;
    const int row16 = (e >> 6) & 15;
    const int qt = (e >> 10) & 127;
    const int b = e >> 17;
    const int nc = (qt >> 2) + 1;
    const int base_id = b * 4096 + qt * 32;

    float M = -3.0e38f;
    for (int c = 0; c < nc; ++c) M = fmaxf(M, mpart[(base_id + c) * 16 + row16]);
    float L = 0.0f, O = 0.0f;
    for (int c = 0; c < nc; ++c) {
        float e_c = __expf(mpart[(base_id + c) * 16 + row16] - M);
        L += e_c * lpart[(base_id + c) * 16 + row16];
        O += e_c * bf2f(Opart[(size_t)(base_id + c) * 1024 + row16 * 64 + col]);
    }
    out[e] = O / L;
}

extern "C" void kernel_launch(void* const* d_in, const int* in_sizes, int n_in,
                              void* d_out, int out_size, void* d_ws, size_t ws_size,
                              hipStream_t stream) {
    const float* x = (const float*)d_in[0];
    const float* Wq = (const float*)d_in[1];
    const float* Wk = (const float*)d_in[2];
    const float* Wv = (const float*)d_in[3];
    float* out = (float*)d_out;

    char* ws = (char*)d_ws;
    unsigned short* wt = (unsigned short*)(ws);
    unsigned short* q = (unsigned short*)(ws + 393216);
    unsigned short* k = (unsigned short*)(ws + 1441792);
    unsigned short* vT = (unsigned short*)(ws + 2490368);
    unsigned short* Opart = (unsigned short*)(ws + 3538944);
    float* mpart = (float*)(ws + 37093376ull);
    float* lpart = (float*)(ws + 38141952ull);

    hipLaunchKernelGGL(wt_kernel, dim3(768), dim3(256), 0, stream, Wq, Wk, Wv, wt);
    hipLaunchKernelGGL(qkv_kernel, dim3(256), dim3(512), 0, stream, x, wt, q, k, vT);
    hipLaunchKernelGGL(attn_partial, dim3(4096), dim3(256), 0, stream, q, k, vT, Opart, mpart, lpart);
    hipLaunchKernelGGL(attn_merge, dim3(2048), dim3(256), 0, stream, Opart, mpart, lpart, out);
}

// Round 7
// 149.469 us; speedup vs baseline: 1.3201x; 1.0631x over previous
//
#include <hip/hip_runtime.h>

// Head: single-head causal attention. B=4, T=2048, D=1024, H=64. fp32 in/out.
// R7: (a) qkv: 512 x 256thr (M=32 x 2 halves), double-buffered LDS -> 2
// independent blocks/CU so barriers overlap across blocks (R6's single
// 512-thr block/CU serialized on its own barrier). (b) attn_partial: 128-key
// chunks (R3's verified 2-tile online softmax), Opart bf16 -> halves partial
// traffic and merge's serial loop. (c) merge flat, nc<=16.
//
// ws layout (bytes):
//   [0,        393216)   Wt    bf16 [192][1024]
//   [393216,  1441792)   q     bf16 [8192][64]
//   [1441792, 2490368)   k     bf16 [8192][64]
//   [2490368, 3538944)   vT    bf16 [4][64][2048]
//   [3538944, 20316160)  Opart bf16 [8192][16][64]  (id = b*2048+qt*16+kc)
//   [20316160,20840448)  mpart fp32 [8192][16]
//   [20840448,21364736)  lpart fp32 [8192][16]

typedef __attribute__((ext_vector_type(8))) __bf16 bf16x8;
typedef __attribute__((ext_vector_type(4))) float floatx4;

union BF8 {
    bf16x8 v;
    unsigned short s[8];
    uint4 u;
};
union BF4 {
    unsigned short s[4];
    unsigned long long ull;
};

__device__ inline unsigned short f2bf(float f) {
    unsigned int u = __float_as_uint(f);
    unsigned int r = (u + 0x7fffu + ((u >> 16) & 1u)) >> 16;
    return (unsigned short)r;
}
__device__ inline float bf2f(unsigned short s) {
    unsigned int u = ((unsigned int)s) << 16;
    return __uint_as_float(u);
}

// ---------------------------------------------------------------------------
// Kernel 0: Wt[n][kk] = bf16(W_{n/64}[kk][n%64])
// ---------------------------------------------------------------------------
__global__ __launch_bounds__(256) void wt_kernel(const float* __restrict__ Wq,
                                                 const float* __restrict__ Wk,
                                                 const float* __restrict__ Wv,
                                                 unsigned short* __restrict__ wt) {
    int idx = blockIdx.x * 256 + threadIdx.x;
    int kk = idx / 192;
    int n = idx - kk * 192;
    int sel = n >> 6;
    int h = n & 63;
    const float* W = (sel == 0) ? Wq : (sel == 1) ? Wk : Wv;
    wt[(size_t)n * 1024 + kk] = f2bf(W[(size_t)kk * 64 + h]);
}

// ---------------------------------------------------------------------------
// Kernel 1: QKV projection. Grid 512 = 256 M-tiles(32 rows) x 2 N-halves
// (96 cols). Block 256 thr / 4 waves: wave w = rows (w&1)*16, cols (w>>1)*48.
// K-chunks of 128 staged fp32->bf16 into padded LDS [32][136], double-
// buffered; staging bursts are contiguous 128-B segments. 2 blocks/CU ->
// cross-block overlap across barrier drains.
// ---------------------------------------------------------------------------
__global__ __launch_bounds__(256) void qkv_kernel(const float* __restrict__ x,
                                                  const unsigned short* __restrict__ wt,
                                                  unsigned short* __restrict__ qo,
                                                  unsigned short* __restrict__ ko,
                                                  unsigned short* __restrict__ vo) {
    __shared__ __align__(16) unsigned short lx[2][32 * 136];
    __shared__ __align__(16) unsigned short vtile[64 * 40];
    const int tid = threadIdx.x;
    const int w = tid >> 6;
    const int rg = w & 1;         // row-group (16 rows)
    const int cg = w >> 1;        // col-group (48 cols)
    const int lane = tid & 63;
    const int quad = lane >> 4;
    const int l16 = lane & 15;
    const int m0 = (blockIdx.x >> 1) * 32;
    const int half = blockIdx.x & 1;

    const int srow = tid >> 3;  // 0..31
    const int sc8 = tid & 7;    // float4 slot

    float4 ld[4];
    const float* xbase = x + (size_t)(m0 + srow) * 1024 + sc8 * 4;

#define LOAD_CHUNK(c)                                                  \
    {                                                                  \
        const float* p_ = xbase + (c) * 128;                           \
        _Pragma("unroll") for (int i_ = 0; i_ < 4; ++i_)               \
            ld[i_] = *(const float4*)(p_ + i_ * 32);                   \
    }
#define WRITE_CHUNK(buf)                                               \
    {                                                                  \
        unsigned short* p_ = &lx[buf][0] + srow * 136 + sc8 * 4;       \
        _Pragma("unroll") for (int i_ = 0; i_ < 4; ++i_) {             \
            BF4 b_;                                                    \
            b_.s[0] = f2bf(ld[i_].x); b_.s[1] = f2bf(ld[i_].y);        \
            b_.s[2] = f2bf(ld[i_].z); b_.s[3] = f2bf(ld[i_].w);        \
            *(unsigned long long*)(p_ + i_ * 32) = b_.ull;             \
        }                                                              \
    }

    floatx4 acc[3];
#pragma unroll
    for (int i = 0; i < 3; ++i) acc[i] = (floatx4)(0.0f);

    LOAD_CHUNK(0);
    WRITE_CHUNK(0);
    __syncthreads();

    for (int c = 0; c < 8; ++c) {
        if (c < 7) LOAD_CHUNK(c + 1);
        const unsigned short* lp = &lx[c & 1][0] + (rg * 16 + l16) * 136 + quad * 8;
        const unsigned short* wp =
            wt + (size_t)(half * 96 + cg * 48 + l16) * 1024 + c * 128 + quad * 8;
#pragma unroll
        for (int kst = 0; kst < 4; ++kst) {
            BF8 a;
            a.u = *(const uint4*)(lp + kst * 32);
#pragma unroll
            for (int nt = 0; nt < 3; ++nt) {
                BF8 b;
                b.u = *(const uint4*)(wp + (size_t)nt * 16 * 1024 + kst * 32);
                acc[nt] = __builtin_amdgcn_mfma_f32_16x16x32_bf16(a.v, b.v, acc[nt], 0, 0, 0);
            }
        }
        if (c < 7) WRITE_CHUNK((c + 1) & 1);
        __syncthreads();
    }

    const int trow = m0 + rg * 16 + quad * 4;
    if (half == 0) {
        // local col ngl = cg*48 + nt*16 in [0,96): ngl<64 -> q, else k h=ngl-64
#pragma unroll
        for (int nt = 0; nt < 3; ++nt) {
            const int ngl = cg * 48 + nt * 16;
            if (ngl < 64) {
#pragma unroll
                for (int r = 0; r < 4; ++r)
                    qo[(size_t)(trow + r) * 64 + ngl + l16] = f2bf(acc[nt][r]);
            } else {
#pragma unroll
                for (int r = 0; r < 4; ++r)
                    ko[(size_t)(trow + r) * 64 + (ngl - 64) + l16] = f2bf(acc[nt][r]);
            }
        }
    } else {
        // n = 96+ngl: ngl<32 -> k h=32+ngl ; else v h=ngl-32 (via LDS transpose)
#pragma unroll
        for (int nt = 0; nt < 3; ++nt) {
            const int ngl = cg * 48 + nt * 16;
            if (ngl < 32) {
#pragma unroll
                for (int r = 0; r < 4; ++r)
                    ko[(size_t)(trow + r) * 64 + 32 + ngl + l16] = f2bf(acc[nt][r]);
            } else {
                const int hv = ngl - 32 + l16;
                BF4 pk;
#pragma unroll
                for (int r = 0; r < 4; ++r) pk.s[r] = f2bf(acc[nt][r]);
                *(unsigned long long*)&vtile[hv * 40 + rg * 16 + quad * 4] = pk.ull;
            }
        }
        __syncthreads();
        const int b = m0 >> 11;
        const int h = tid >> 2;
        const int seg = tid & 3;
        uint4 v0 = *(const uint4*)&vtile[h * 40 + seg * 8];
        unsigned short* dst = vo + (size_t)(b * 64 + h) * 2048 + (m0 & 2047) + seg * 8;
        *(uint4*)dst = v0;
    }
#undef LOAD_CHUNK
#undef WRITE_CHUNK
}

// ---------------------------------------------------------------------------
// Kernel 2: split-K flash pass A, 128-key chunks. id in [0,8192):
// b=id>>11, qt=(id>>4)&127, kc=id&15. Active iff kc <= qt>>3 (4352 waves).
// <=2 K-tiles of 64 with online softmax; O-partials bf16, m/l fp32.
// ---------------------------------------------------------------------------
__global__ __launch_bounds__(256) void attn_partial(const unsigned short* __restrict__ qi,
                                                    const unsigned short* __restrict__ ki,
                                                    const unsigned short* __restrict__ vT,
                                                    unsigned short* __restrict__ Opart,
                                                    float* __restrict__ mpart,
                                                    float* __restrict__ lpart) {
    __shared__ __align__(16) unsigned short lds_p[4 * 16 * 72];
    const int tid = threadIdx.x;
    const int w = tid >> 6;
    const int lane = tid & 63;
    const int quad = lane >> 4;
    const int l16 = lane & 15;
    const int id = blockIdx.x * 4 + w;
    const int b = id >> 11;
    const int qt = (id >> 4) & 127;
    const int kc = id & 15;
    if (kc > (qt >> 3)) return;
    const int r0 = qt * 16;

    BF8 aq[2];
    {
        const unsigned short* qp = qi + (size_t)(b * 2048 + r0 + l16) * 64 + quad * 8;
        aq[0].u = *(const uint4*)(qp);
        aq[1].u = *(const uint4*)(qp + 32);
    }

    floatx4 oacc[4];
#pragma unroll
    for (int nt = 0; nt < 4; ++nt) oacc[nt] = (floatx4)(0.0f);
    float m_i[4], l_i[4];
#pragma unroll
    for (int r = 0; r < 4; ++r) { m_i[r] = -3.0e38f; l_i[r] = 0.0f; }

    unsigned short* myp = lds_p + w * (16 * 72);

    for (int t = 0; t < 2; ++t) {
        const int j0 = kc * 128 + t * 64;
        if (j0 > r0 + 15) break;

        floatx4 s[4];
#pragma unroll
        for (int nt = 0; nt < 4; ++nt) s[nt] = (floatx4)(0.0f);
#pragma unroll
        for (int kst = 0; kst < 2; ++kst) {
#pragma unroll
            for (int nt = 0; nt < 4; ++nt) {
                BF8 bk;
                bk.u = *(const uint4*)(ki + (size_t)(b * 2048 + j0 + nt * 16 + l16) * 64 +
                                       kst * 32 + quad * 8);
                s[nt] = __builtin_amdgcn_mfma_f32_16x16x32_bf16(aq[kst].v, bk.v, s[nt], 0, 0, 0);
            }
        }

        float sv[4][4];
        const bool masked = (j0 + 63 > r0);
#pragma unroll
        for (int nt = 0; nt < 4; ++nt)
#pragma unroll
            for (int r = 0; r < 4; ++r) {
                float val = s[nt][r] * 0.125f;
                if (masked) {
                    int key = j0 + nt * 16 + l16;
                    int qr = r0 + quad * 4 + r;
                    if (key > qr) val = -3.0e38f;
                }
                sv[nt][r] = val;
            }

        float alpha[4];
#pragma unroll
        for (int r = 0; r < 4; ++r) {
            float mx = fmaxf(fmaxf(sv[0][r], sv[1][r]), fmaxf(sv[2][r], sv[3][r]));
            mx = fmaxf(mx, __shfl_xor(mx, 1));
            mx = fmaxf(mx, __shfl_xor(mx, 2));
            mx = fmaxf(mx, __shfl_xor(mx, 4));
            mx = fmaxf(mx, __shfl_xor(mx, 8));
            float mn = fmaxf(m_i[r], mx);
            alpha[r] = __expf(m_i[r] - mn);
            m_i[r] = mn;
        }
        float rs[4] = {0.f, 0.f, 0.f, 0.f};
#pragma unroll
        for (int nt = 0; nt < 4; ++nt)
#pragma unroll
            for (int r = 0; r < 4; ++r) {
                float p = __expf(sv[nt][r] - m_i[r]);
                sv[nt][r] = p;
                rs[r] += p;
            }
#pragma unroll
        for (int r = 0; r < 4; ++r) {
            float t2 = rs[r];
            t2 += __shfl_xor(t2, 1);
            t2 += __shfl_xor(t2, 2);
            t2 += __shfl_xor(t2, 4);
            t2 += __shfl_xor(t2, 8);
            l_i[r] = l_i[r] * alpha[r] + t2;
        }
#pragma unroll
        for (int nt = 0; nt < 4; ++nt)
#pragma unroll
            for (int r = 0; r < 4; ++r) oacc[nt][r] *= alpha[r];

#pragma unroll
        for (int nt = 0; nt < 4; ++nt)
#pragma unroll
            for (int r = 0; r < 4; ++r)
                myp[(quad * 4 + r) * 72 + nt * 16 + l16] = f2bf(sv[nt][r]);

#pragma unroll
        for (int kst = 0; kst < 2; ++kst) {
            BF8 ap;
            ap.u = *(const uint4*)(myp + l16 * 72 + kst * 32 + quad * 8);
#pragma unroll
            for (int nt = 0; nt < 4; ++nt) {
                BF8 bv;
                bv.u = *(const uint4*)(vT + (size_t)(b * 64 + nt * 16 + l16) * 2048 + j0 +
                                       kst * 32 + quad * 8);
                oacc[nt] = __builtin_amdgcn_mfma_f32_16x16x32_bf16(ap.v, bv.v, oacc[nt], 0, 0, 0);
            }
        }
    }

    const size_t ob = (size_t)id * 1024;
#pragma unroll
    for (int nt = 0; nt < 4; ++nt)
#pragma unroll
        for (int r = 0; r < 4; ++r)
            Opart[ob + (quad * 4 + r) * 64 + nt * 16 + l16] = f2bf(oacc[nt][r]);
    if (l16 == 0) {
#pragma unroll
        for (int r = 0; r < 4; ++r) {
            mpart[id * 16 + quad * 4 + r] = m_i[r];
            lpart[id * 16 + quad * 4 + r] = l_i[r];
        }
    }
}

// ---------------------------------------------------------------------------
// Kernel 3: merge, flat. One thread per output element (524288), 2048 blocks.
// nc = (qt>>3)+1 <= 16. Opart reads 128-B coalesced; m/l wave-uniform.
// ---------------------------------------------------------------------------
__global__ __launch_bounds__(256) void attn_merge(const unsigned short* __restrict__ Opart,
                                                  const float* __restrict__ mpart,
                                                  const float* __restrict__ lpart,
                                                  float* __restrict__ out) {
    const int e = blockIdx.x * 256 + threadIdx.x;
    const int col = e & 63;
    const int t = (e >> 6) & 2047;
    const int b = e >> 17;
    const int qt = t >> 4;
    const int row16 = t & 15;
    const int nc = (qt >> 3) + 1;
    const int base_id = b * 2048 + qt * 16;

    float M = -3.0e38f;
    for (int c = 0; c < nc; ++c) M = fmaxf(M, mpart[(base_id + c) * 16 + row16]);
    float L = 0.0f, O = 0.0f;
    for (int c = 0; c < nc; ++c) {
        float e_c = __expf(mpart[(base_id + c) * 16 + row16] - M);
        L += e_c * lpart[(base_id + c) * 16 + row16];
        O += e_c * bf2f(Opart[(size_t)(base_id + c) * 1024 + row16 * 64 + col]);
    }
    out[e] = O / L;
}

extern "C" void kernel_launch(void* const* d_in, const int* in_sizes, int n_in,
                              void* d_out, int out_size, void* d_ws, size_t ws_size,
                              hipStream_t stream) {
    const float* x = (const float*)d_in[0];
    const float* Wq = (const float*)d_in[1];
    const float* Wk = (const float*)d_in[2];
    const float* Wv = (const float*)d_in[3];
    float* out = (float*)d_out;

    char* ws = (char*)d_ws;
    unsigned short* wt = (unsigned short*)(ws);
    unsigned short* q = (unsigned short*)(ws + 393216);
    unsigned short* k = (unsigned short*)(ws + 1441792);
    unsigned short* vT = (unsigned short*)(ws + 2490368);
    unsigned short* Opart = (unsigned short*)(ws + 3538944);
    float* mpart = (float*)(ws + 20316160ull);
    float* lpart = (float*)(ws + 20840448ull);

    hipLaunchKernelGGL(wt_kernel, dim3(768), dim3(256), 0, stream, Wq, Wk, Wv, wt);
    hipLaunchKernelGGL(qkv_kernel, dim3(512), dim3(256), 0, stream, x, wt, q, k, vT);
    hipLaunchKernelGGL(attn_partial, dim3(2048), dim3(256), 0, stream, q, k, vT, Opart, mpart, lpart);
    hipLaunchKernelGGL(attn_merge, dim3(2048), dim3(256), 0, stream, Opart, mpart, lpart, out);
}

// Round 8
// 132.266 us; speedup vs baseline: 1.4918x; 1.1301x over previous
//
#include <hip/hip_runtime.h>

// Head: single-head causal attention. B=4, T=2048, D=1024, H=64. fp32 in/out.
// R8: kill remaining strided patterns.
//  - W transposed into FRAGMENT layout wtf[nblk][koct][l16][8] so qkv B-frag
//    loads are 4x256B contiguous per instruction (was 16 lines 2KB apart).
//  - wt_kernel: LDS tile transpose, coalesced both sides (was 196K scattered
//    2B stores across 2KB-strided lines).
//  - merge: single-pass online rescale (was 2 serial dependent passes).
//  attn_partial unchanged (control).
//
// ws layout (bytes):
//   [0,        393216)   wtf   bf16 [12][128][16][8]  (fragment-ordered W^T)
//   [393216,  1441792)   q     bf16 [8192][64]
//   [1441792, 2490368)   k     bf16 [8192][64]
//   [2490368, 3538944)   vT    bf16 [4][64][2048]
//   [3538944, 20316160)  Opart bf16 [8192][16][64]  (id = b*2048+qt*16+kc)
//   [20316160,20840448)  mpart fp32 [8192][16]
//   [20840448,21364736)  lpart fp32 [8192][16]

typedef __attribute__((ext_vector_type(8))) __bf16 bf16x8;
typedef __attribute__((ext_vector_type(4))) float floatx4;

union BF8 {
    bf16x8 v;
    unsigned short s[8];
    uint4 u;
};
union BF4 {
    unsigned short s[4];
    unsigned long long ull;
};

__device__ inline unsigned short f2bf(float f) {
    unsigned int u = __float_as_uint(f);
    unsigned int r = (u + 0x7fffu + ((u >> 16) & 1u)) >> 16;
    return (unsigned short)r;
}
__device__ inline float bf2f(unsigned short s) {
    unsigned int u = ((unsigned int)s) << 16;
    return __uint_as_float(u);
}

// ---------------------------------------------------------------------------
// Kernel 0: W -> wtf fragment layout. Grid 48 = 3 matrices x 16 kk-tiles(64).
// Stage 1: read W[kk][h] in 1KB coalesced bursts -> bf16 LDS [64][72].
// Stage 2: each thread emits two 16B segments wtf[nblk][koct][l16][8];
// 16 consecutive threads -> 256B contiguous runs. All coalesced.
// ---------------------------------------------------------------------------
__global__ __launch_bounds__(256) void wt_kernel(const float* __restrict__ Wq,
                                                 const float* __restrict__ Wk,
                                                 const float* __restrict__ Wv,
                                                 unsigned short* __restrict__ wtf) {
    __shared__ __align__(16) unsigned short lt[64 * 72];
    const int tid = threadIdx.x;
    const int sel = blockIdx.x >> 4;
    const int kb = blockIdx.x & 15;
    const float* W = (sel == 0) ? Wq : (sel == 1) ? Wk : Wv;

    const int h = tid & 63;
    const int kr = tid >> 6;  // 0..3
#pragma unroll
    for (int i = 0; i < 16; ++i) {
        const int kkl = kr + i * 4;
        lt[kkl * 72 + h] = f2bf(W[(size_t)(kb * 64 + kkl) * 64 + h]);
    }
    __syncthreads();

#pragma unroll
    for (int s = 0; s < 2; ++s) {
        const int seg = tid + s * 256;      // 0..511
        const int l16 = seg & 15;
        const int rest = seg >> 4;          // 0..31
        const int ko = rest & 7;            // koct within tile
        const int hb = rest >> 3;           // 0..3
        const int hh = hb * 16 + l16;       // 0..63
        BF8 o;
#pragma unroll
        for (int j = 0; j < 8; ++j) o.s[j] = lt[(ko * 8 + j) * 72 + hh];
        const int nblk = sel * 4 + hb;
        const int koct = kb * 8 + ko;
        *(uint4*)(wtf + ((size_t)nblk * 128 + koct) * 128 + l16 * 8) = o.u;
    }
}

// ---------------------------------------------------------------------------
// Kernel 1: QKV projection. Grid 512 = 256 M-tiles(32 rows) x 2 N-halves
// (96 cols). Block 256 thr / 4 waves: wave w = rows (w&1)*16, cols (w>>1)*48.
// K-chunks of 128: x staged fp32->bf16 into padded LDS [32][136] (double-
// buffered, contiguous 128B bursts); B-frags from wtf (contiguous 256B runs).
// ---------------------------------------------------------------------------
__global__ __launch_bounds__(256) void qkv_kernel(const float* __restrict__ x,
                                                  const unsigned short* __restrict__ wtf,
                                                  unsigned short* __restrict__ qo,
                                                  unsigned short* __restrict__ ko,
                                                  unsigned short* __restrict__ vo) {
    __shared__ __align__(16) unsigned short lx[2][32 * 136];
    __shared__ __align__(16) unsigned short vtile[64 * 40];
    const int tid = threadIdx.x;
    const int w = tid >> 6;
    const int rg = w & 1;         // row-group (16 rows)
    const int cg = w >> 1;        // col-group (48 cols)
    const int lane = tid & 63;
    const int quad = lane >> 4;
    const int l16 = lane & 15;
    const int m0 = (blockIdx.x >> 1) * 32;
    const int half = blockIdx.x & 1;

    const int srow = tid >> 3;  // 0..31
    const int sc8 = tid & 7;    // float4 slot

    float4 ld[4];
    const float* xbase = x + (size_t)(m0 + srow) * 1024 + sc8 * 4;

#define LOAD_CHUNK(c)                                                  \
    {                                                                  \
        const float* p_ = xbase + (c) * 128;                           \
        _Pragma("unroll") for (int i_ = 0; i_ < 4; ++i_)               \
            ld[i_] = *(const float4*)(p_ + i_ * 32);                   \
    }
#define WRITE_CHUNK(buf)                                               \
    {                                                                  \
        unsigned short* p_ = &lx[buf][0] + srow * 136 + sc8 * 4;       \
        _Pragma("unroll") for (int i_ = 0; i_ < 4; ++i_) {             \
            BF4 b_;                                                    \
            b_.s[0] = f2bf(ld[i_].x); b_.s[1] = f2bf(ld[i_].y);        \
            b_.s[2] = f2bf(ld[i_].z); b_.s[3] = f2bf(ld[i_].w);        \
            *(unsigned long long*)(p_ + i_ * 32) = b_.ull;             \
        }                                                              \
    }

    floatx4 acc[3];
#pragma unroll
    for (int i = 0; i < 3; ++i) acc[i] = (floatx4)(0.0f);

    const int nb0 = half * 6 + cg * 3;  // wave's first n-block

    LOAD_CHUNK(0);
    WRITE_CHUNK(0);
    __syncthreads();

    for (int c = 0; c < 8; ++c) {
        if (c < 7) LOAD_CHUNK(c + 1);
        const unsigned short* lp = &lx[c & 1][0] + (rg * 16 + l16) * 136 + quad * 8;
#pragma unroll
        for (int kst = 0; kst < 4; ++kst) {
            BF8 a;
            a.u = *(const uint4*)(lp + kst * 32);
            const int koct = c * 16 + kst * 4 + quad;
#pragma unroll
            for (int nt = 0; nt < 3; ++nt) {
                BF8 b;
                b.u = *(const uint4*)(wtf + ((size_t)(nb0 + nt) * 128 + koct) * 128 + l16 * 8);
                acc[nt] = __builtin_amdgcn_mfma_f32_16x16x32_bf16(a.v, b.v, acc[nt], 0, 0, 0);
            }
        }
        if (c < 7) WRITE_CHUNK((c + 1) & 1);
        __syncthreads();
    }

    const int trow = m0 + rg * 16 + quad * 4;
    if (half == 0) {
#pragma unroll
        for (int nt = 0; nt < 3; ++nt) {
            const int ngl = cg * 48 + nt * 16;
            if (ngl < 64) {
#pragma unroll
                for (int r = 0; r < 4; ++r)
                    qo[(size_t)(trow + r) * 64 + ngl + l16] = f2bf(acc[nt][r]);
            } else {
#pragma unroll
                for (int r = 0; r < 4; ++r)
                    ko[(size_t)(trow + r) * 64 + (ngl - 64) + l16] = f2bf(acc[nt][r]);
            }
        }
    } else {
#pragma unroll
        for (int nt = 0; nt < 3; ++nt) {
            const int ngl = cg * 48 + nt * 16;
            if (ngl < 32) {
#pragma unroll
                for (int r = 0; r < 4; ++r)
                    ko[(size_t)(trow + r) * 64 + 32 + ngl + l16] = f2bf(acc[nt][r]);
            } else {
                const int hv = ngl - 32 + l16;
                BF4 pk;
#pragma unroll
                for (int r = 0; r < 4; ++r) pk.s[r] = f2bf(acc[nt][r]);
                *(unsigned long long*)&vtile[hv * 40 + rg * 16 + quad * 4] = pk.ull;
            }
        }
        __syncthreads();
        const int b = m0 >> 11;
        const int h = tid >> 2;
        const int seg = tid & 3;
        uint4 v0 = *(const uint4*)&vtile[h * 40 + seg * 8];
        unsigned short* dst = vo + (size_t)(b * 64 + h) * 2048 + (m0 & 2047) + seg * 8;
        *(uint4*)dst = v0;
    }
#undef LOAD_CHUNK
#undef WRITE_CHUNK
}

// ---------------------------------------------------------------------------
// Kernel 2: split-K flash pass A, 128-key chunks (unchanged R7 control).
// id in [0,8192): b=id>>11, qt=(id>>4)&127, kc=id&15; active iff kc<=qt>>3.
// ---------------------------------------------------------------------------
__global__ __launch_bounds__(256) void attn_partial(const unsigned short* __restrict__ qi,
                                                    const unsigned short* __restrict__ ki,
                                                    const unsigned short* __restrict__ vT,
                                                    unsigned short* __restrict__ Opart,
                                                    float* __restrict__ mpart,
                                                    float* __restrict__ lpart) {
    __shared__ __align__(16) unsigned short lds_p[4 * 16 * 72];
    const int tid = threadIdx.x;
    const int w = tid >> 6;
    const int lane = tid & 63;
    const int quad = lane >> 4;
    const int l16 = lane & 15;
    const int id = blockIdx.x * 4 + w;
    const int b = id >> 11;
    const int qt = (id >> 4) & 127;
    const int kc = id & 15;
    if (kc > (qt >> 3)) return;
    const int r0 = qt * 16;

    BF8 aq[2];
    {
        const unsigned short* qp = qi + (size_t)(b * 2048 + r0 + l16) * 64 + quad * 8;
        aq[0].u = *(const uint4*)(qp);
        aq[1].u = *(const uint4*)(qp + 32);
    }

    floatx4 oacc[4];
#pragma unroll
    for (int nt = 0; nt < 4; ++nt) oacc[nt] = (floatx4)(0.0f);
    float m_i[4], l_i[4];
#pragma unroll
    for (int r = 0; r < 4; ++r) { m_i[r] = -3.0e38f; l_i[r] = 0.0f; }

    unsigned short* myp = lds_p + w * (16 * 72);

    for (int t = 0; t < 2; ++t) {
        const int j0 = kc * 128 + t * 64;
        if (j0 > r0 + 15) break;

        floatx4 s[4];
#pragma unroll
        for (int nt = 0; nt < 4; ++nt) s[nt] = (floatx4)(0.0f);
#pragma unroll
        for (int kst = 0; kst < 2; ++kst) {
#pragma unroll
            for (int nt = 0; nt < 4; ++nt) {
                BF8 bk;
                bk.u = *(const uint4*)(ki + (size_t)(b * 2048 + j0 + nt * 16 + l16) * 64 +
                                       kst * 32 + quad * 8);
                s[nt] = __builtin_amdgcn_mfma_f32_16x16x32_bf16(aq[kst].v, bk.v, s[nt], 0, 0, 0);
            }
        }

        float sv[4][4];
        const bool masked = (j0 + 63 > r0);
#pragma unroll
        for (int nt = 0; nt < 4; ++nt)
#pragma unroll
            for (int r = 0; r < 4; ++r) {
                float val = s[nt][r] * 0.125f;
                if (masked) {
                    int key = j0 + nt * 16 + l16;
                    int qr = r0 + quad * 4 + r;
                    if (key > qr) val = -3.0e38f;
                }
                sv[nt][r] = val;
            }

        float alpha[4];
#pragma unroll
        for (int r = 0; r < 4; ++r) {
            float mx = fmaxf(fmaxf(sv[0][r], sv[1][r]), fmaxf(sv[2][r], sv[3][r]));
            mx = fmaxf(mx, __shfl_xor(mx, 1));
            mx = fmaxf(mx, __shfl_xor(mx, 2));
            mx = fmaxf(mx, __shfl_xor(mx, 4));
            mx = fmaxf(mx, __shfl_xor(mx, 8));
            float mn = fmaxf(m_i[r], mx);
            alpha[r] = __expf(m_i[r] - mn);
            m_i[r] = mn;
        }
        float rs[4] = {0.f, 0.f, 0.f, 0.f};
#pragma unroll
        for (int nt = 0; nt < 4; ++nt)
#pragma unroll
            for (int r = 0; r < 4; ++r) {
                float p = __expf(sv[nt][r] - m_i[r]);
                sv[nt][r] = p;
                rs[r] += p;
            }
#pragma unroll
        for (int r = 0; r < 4; ++r) {
            float t2 = rs[r];
            t2 += __shfl_xor(t2, 1);
            t2 += __shfl_xor(t2, 2);
            t2 += __shfl_xor(t2, 4);
            t2 += __shfl_xor(t2, 8);
            l_i[r] = l_i[r] * alpha[r] + t2;
        }
#pragma unroll
        for (int nt = 0; nt < 4; ++nt)
#pragma unroll
            for (int r = 0; r < 4; ++r) oacc[nt][r] *= alpha[r];

#pragma unroll
        for (int nt = 0; nt < 4; ++nt)
#pragma unroll
            for (int r = 0; r < 4; ++r)
                myp[(quad * 4 + r) * 72 + nt * 16 + l16] = f2bf(sv[nt][r]);

#pragma unroll
        for (int kst = 0; kst < 2; ++kst) {
            BF8 ap;
            ap.u = *(const uint4*)(myp + l16 * 72 + kst * 32 + quad * 8);
#pragma unroll
            for (int nt = 0; nt < 4; ++nt) {
                BF8 bv;
                bv.u = *(const uint4*)(vT + (size_t)(b * 64 + nt * 16 + l16) * 2048 + j0 +
                                       kst * 32 + quad * 8);
                oacc[nt] = __builtin_amdgcn_mfma_f32_16x16x32_bf16(ap.v, bv.v, oacc[nt], 0, 0, 0);
            }
        }
    }

    const size_t ob = (size_t)id * 1024;
#pragma unroll
    for (int nt = 0; nt < 4; ++nt)
#pragma unroll
        for (int r = 0; r < 4; ++r)
            Opart[ob + (quad * 4 + r) * 64 + nt * 16 + l16] = f2bf(oacc[nt][r]);
    if (l16 == 0) {
#pragma unroll
        for (int r = 0; r < 4; ++r) {
            mpart[id * 16 + quad * 4 + r] = m_i[r];
            lpart[id * 16 + quad * 4 + r] = l_i[r];
        }
    }
}

// ---------------------------------------------------------------------------
// Kernel 3: merge, flat + ONLINE single pass. One thread per output element
// (524288), 2048 blocks. nc=(qt>>3)+1<=16. Rescale-accumulate per partial:
// one pass over m/l/O instead of two dependent passes.
// ---------------------------------------------------------------------------
__global__ __launch_bounds__(256) void attn_merge(const unsigned short* __restrict__ Opart,
                                                  const float* __restrict__ mpart,
                                                  const float* __restrict__ lpart,
                                                  float* __restrict__ out) {
    const int e = blockIdx.x * 256 + threadIdx.x;
    const int col = e & 63;
    const int t = (e >> 6) & 2047;
    const int b = e >> 17;
    const int qt = t >> 4;
    const int row16 = t & 15;
    const int nc = (qt >> 3) + 1;
    const int base_id = b * 2048 + qt * 16;

    float M = -3.0e38f, L = 0.0f, O = 0.0f;
#pragma unroll 4
    for (int c = 0; c < nc; ++c) {
        const float m_c = mpart[(base_id + c) * 16 + row16];
        const float l_c = lpart[(base_id + c) * 16 + row16];
        const float o_c = bf2f(Opart[(size_t)(base_id + c) * 1024 + row16 * 64 + col]);
        const float Mn = fmaxf(M, m_c);
        const float a = __expf(M - Mn);
        const float ec = __expf(m_c - Mn);
        L = L * a + ec * l_c;
        O = O * a + ec * o_c;
        M = Mn;
    }
    out[e] = O / L;
}

extern "C" void kernel_launch(void* const* d_in, const int* in_sizes, int n_in,
                              void* d_out, int out_size, void* d_ws, size_t ws_size,
                              hipStream_t stream) {
    const float* x = (const float*)d_in[0];
    const float* Wq = (const float*)d_in[1];
    const float* Wk = (const float*)d_in[2];
    const float* Wv = (const float*)d_in[3];
    float* out = (float*)d_out;

    char* ws = (char*)d_ws;
    unsigned short* wtf = (unsigned short*)(ws);
    unsigned short* q = (unsigned short*)(ws + 393216);
    unsigned short* k = (unsigned short*)(ws + 1441792);
    unsigned short* vT = (unsigned short*)(ws + 2490368);
    unsigned short* Opart = (unsigned short*)(ws + 3538944);
    float* mpart = (float*)(ws + 20316160ull);
    float* lpart = (float*)(ws + 20840448ull);

    hipLaunchKernelGGL(wt_kernel, dim3(48), dim3(256), 0, stream, Wq, Wk, Wv, wtf);
    hipLaunchKernelGGL(qkv_kernel, dim3(512), dim3(256), 0, stream, x, wtf, q, k, vT);
    hipLaunchKernelGGL(attn_partial, dim3(2048), dim3(256), 0, stream, q, k, vT, Opart, mpart, lpart);
    hipLaunchKernelGGL(attn_merge, dim3(2048), dim3(256), 0, stream, Opart, mpart, lpart, out);
}

// Round 9
// 106.008 us; speedup vs baseline: 1.8613x; 1.2477x over previous
//
#include <hip/hip_runtime.h>

// Head: single-head causal attention. B=4, T=2048, D=1024, H=64. fp32 in/out.
// R9: fragment-layout everything.
//  - qkv writes q/k/v directly in MFMA fragment order [tile][koct][l16][8]
//    (LDS transpose epilogue) -> every attn_partial global load is a
//    contiguous 1KB wave load (base + kst*512 + lane*8). R8's attn loads
//    were 16-line scatters.
//  - qkv re-tiled: 512 blocks x (16 rows x 192 cols); x read ONCE (33.5MB,
//    was 67MB), 2 blocks/CU.
//  - attn_partial: compact triangular grid, 1088 blocks = 4352 waves, all
//    active (was 47% no-op waves). Opart 16.7 -> 8.9 MB.
//
// ws layout (bytes):
//   [0,        393216)   wtf   bf16 [12][128][16][8]   (fragment-ordered W)
//   [393216,  1441792)   qf    bf16 [512][8][16][8]    (fragment-ordered Q)
//   [1441792, 2490368)   kf    bf16 [512][8][16][8]
//   [2490368, 3538944)   vf    bf16 [4][32][4][8][16][8]
//   [3538944, 12451840)  Opart bf16 [4352][16][64]     (gid-indexed)
//   [12451840,12730368)  mpart fp32 [4352][16]
//   [12730368,13008896)  lpart fp32 [4352][16]

typedef __attribute__((ext_vector_type(8))) __bf16 bf16x8;
typedef __attribute__((ext_vector_type(4))) float floatx4;

union BF8 {
    bf16x8 v;
    unsigned short s[8];
    uint4 u;
};
union BF4 {
    unsigned short s[4];
    unsigned long long ull;
};

__device__ inline unsigned short f2bf(float f) {
    unsigned int u = __float_as_uint(f);
    unsigned int r = (u + 0x7fffu + ((u >> 16) & 1u)) >> 16;
    return (unsigned short)r;
}
__device__ inline float bf2f(unsigned short s) {
    unsigned int u = ((unsigned int)s) << 16;
    return __uint_as_float(u);
}

// ---------------------------------------------------------------------------
// Kernel 0: W -> wtf fragment layout (unchanged R8). Grid 48 = 3 x 16.
// ---------------------------------------------------------------------------
__global__ __launch_bounds__(256) void wt_kernel(const float* __restrict__ Wq,
                                                 const float* __restrict__ Wk,
                                                 const float* __restrict__ Wv,
                                                 unsigned short* __restrict__ wtf) {
    __shared__ __align__(16) unsigned short lt[64 * 72];
    const int tid = threadIdx.x;
    const int sel = blockIdx.x >> 4;
    const int kb = blockIdx.x & 15;
    const float* W = (sel == 0) ? Wq : (sel == 1) ? Wk : Wv;

    const int h = tid & 63;
    const int kr = tid >> 6;
#pragma unroll
    for (int i = 0; i < 16; ++i) {
        const int kkl = kr + i * 4;
        lt[kkl * 72 + h] = f2bf(W[(size_t)(kb * 64 + kkl) * 64 + h]);
    }
    __syncthreads();

#pragma unroll
    for (int s = 0; s < 2; ++s) {
        const int seg = tid + s * 256;
        const int l16 = seg & 15;
        const int rest = seg >> 4;
        const int ko = rest & 7;
        const int hb = rest >> 3;
        const int hh = hb * 16 + l16;
        BF8 o;
#pragma unroll
        for (int j = 0; j < 8; ++j) o.s[j] = lt[(ko * 8 + j) * 72 + hh];
        const int nblk = sel * 4 + hb;
        const int koct = kb * 8 + ko;
        *(uint4*)(wtf + ((size_t)nblk * 128 + koct) * 128 + l16 * 8) = o.u;
    }
}

// ---------------------------------------------------------------------------
// Kernel 1: QKV projection. Grid 512 m-tiles(16 rows) x 256 thr / 4 waves;
// wave w covers cols w*48..w*48+47 (192 total = q64|k64|v64). K-chunks of
// 128: x staged fp32->bf16 into LDS [16][136] double-buffered (contiguous
// bursts). Epilogue: C-tiles -> LDS transpose -> fragment-layout qf/kf/vf
// (coalesced 256B runs).
// ---------------------------------------------------------------------------
__global__ __launch_bounds__(256) void qkv_kernel(const float* __restrict__ x,
                                                  const unsigned short* __restrict__ wtf,
                                                  unsigned short* __restrict__ qf,
                                                  unsigned short* __restrict__ kf,
                                                  unsigned short* __restrict__ vf) {
    __shared__ __align__(16) unsigned short lx[2][16 * 136];
    __shared__ __align__(16) unsigned short lt[16 * 200];
    __shared__ __align__(16) unsigned short vtile[64 * 24];
    const int tid = threadIdx.x;
    const int w = tid >> 6;  // col-group: 48 cols each
    const int lane = tid & 63;
    const int quad = lane >> 4;
    const int l16 = lane & 15;
    const int m0 = blockIdx.x * 16;
    const int b = m0 >> 11;

    const int srow = tid >> 4;  // 0..15
    const int sc = tid & 15;    // float4 slot (2 per thread: sc, sc+16)

    float4 ld[2];
    const float* xbase = x + (size_t)(m0 + srow) * 1024 + sc * 4;

#define LOAD_CHUNK(c)                               \
    {                                               \
        const float* p_ = xbase + (c) * 128;        \
        ld[0] = *(const float4*)(p_);               \
        ld[1] = *(const float4*)(p_ + 64);          \
    }
#define WRITE_CHUNK(buf)                                           \
    {                                                              \
        unsigned short* p_ = &lx[buf][0] + srow * 136 + sc * 4;    \
        BF4 b0_, b1_;                                              \
        b0_.s[0] = f2bf(ld[0].x); b0_.s[1] = f2bf(ld[0].y);        \
        b0_.s[2] = f2bf(ld[0].z); b0_.s[3] = f2bf(ld[0].w);        \
        b1_.s[0] = f2bf(ld[1].x); b1_.s[1] = f2bf(ld[1].y);        \
        b1_.s[2] = f2bf(ld[1].z); b1_.s[3] = f2bf(ld[1].w);        \
        *(unsigned long long*)(p_) = b0_.ull;                      \
        *(unsigned long long*)(p_ + 64) = b1_.ull;                 \
    }

    floatx4 acc[3];
#pragma unroll
    for (int i = 0; i < 3; ++i) acc[i] = (floatx4)(0.0f);

    LOAD_CHUNK(0);
    WRITE_CHUNK(0);
    __syncthreads();

    for (int c = 0; c < 8; ++c) {
        if (c < 7) LOAD_CHUNK(c + 1);
        const unsigned short* lp = &lx[c & 1][0] + l16 * 136 + quad * 8;
#pragma unroll
        for (int kst = 0; kst < 4; ++kst) {
            BF8 a;
            a.u = *(const uint4*)(lp + kst * 32);
            const int koct = c * 16 + kst * 4 + quad;
#pragma unroll
            for (int nt = 0; nt < 3; ++nt) {
                const int nb = w * 3 + nt;
                BF8 bfr;
                bfr.u = *(const uint4*)(wtf + ((size_t)nb * 128 + koct) * 128 + l16 * 8);
                acc[nt] = __builtin_amdgcn_mfma_f32_16x16x32_bf16(a.v, bfr.v, acc[nt], 0, 0, 0);
            }
        }
        if (c < 7) WRITE_CHUNK((c + 1) & 1);
        __syncthreads();
    }

    // epilogue: stash C-tiles. cols 0..127 (q,k) -> lt row-major; 128..191 (v)
    // -> vtile (4 consecutive t packed per lane).
#pragma unroll
    for (int nt = 0; nt < 3; ++nt) {
        const int ngl = w * 48 + nt * 16;
        if (ngl < 128) {
#pragma unroll
            for (int r = 0; r < 4; ++r)
                lt[(quad * 4 + r) * 200 + ngl + l16] = f2bf(acc[nt][r]);
        } else {
            BF4 pk;
#pragma unroll
            for (int r = 0; r < 4; ++r) pk.s[r] = f2bf(acc[nt][r]);
            *(unsigned long long*)&vtile[(ngl - 128 + l16) * 24 + quad * 4] = pk.ull;
        }
    }
    __syncthreads();

    // q/k emission: 256 segs of 16B; 16 consecutive tids -> 256B contiguous.
    {
        const int row = tid & 15;
        const int koct = tid >> 4;  // 0..15
        uint4 seg = *(const uint4*)&lt[row * 200 + koct * 8];
        const size_t tile = blockIdx.x;  // = b*128 + qt
        if (koct < 8)
            *(uint4*)(qf + tile * 1024 + koct * 128 + row * 8) = seg;
        else
            *(uint4*)(kf + tile * 1024 + (koct - 8) * 128 + row * 8) = seg;
    }
    // v emission: 128 segs of 16B (8 consecutive t at fixed h).
    if (tid < 128) {
        const int h = tid >> 1;
        const int sg = tid & 1;
        uint4 seg = *(const uint4*)&vtile[h * 24 + sg * 8];
        const int jt = (m0 & 2047) >> 6;
        const int koct = ((m0 & 63) >> 3) + sg;
        *(uint4*)(vf + (((size_t)(b * 32 + jt) * 4 + (h >> 4)) * 8 + koct) * 128 +
                  (h & 15) * 8) = seg;
    }
#undef LOAD_CHUNK
#undef WRITE_CHUNK
}

// ---------------------------------------------------------------------------
// Kernel 2: flash pass A, compact triangular grid. 1088 blocks x 4 waves =
// 4352 waves, ALL active. gid -> (b, qt, kc) via sqrt decode of group
// g = qt>>3 (count C(g) = 4g(g+1) per batch). <=2 K-tiles of 64, online
// softmax. Every global load = contiguous 1KB (fragment layouts).
// ---------------------------------------------------------------------------
__global__ __launch_bounds__(256) void attn_partial(const unsigned short* __restrict__ qf,
                                                    const unsigned short* __restrict__ kf,
                                                    const unsigned short* __restrict__ vf,
                                                    unsigned short* __restrict__ Opart,
                                                    float* __restrict__ mpart,
                                                    float* __restrict__ lpart) {
    __shared__ __align__(16) unsigned short lds_p[4 * 16 * 72];
    const int tid = threadIdx.x;
    const int w = tid >> 6;
    const int lane = tid & 63;
    const int quad = lane >> 4;
    const int l16 = lane & 15;
    const int gid = blockIdx.x * 4 + w;  // 0..4351
    const int b = gid / 1088;
    const int rem = gid - b * 1088;
    int g = (int)((sqrtf((float)(4 * rem + 1)) - 1.0f) * 0.5f);
    while (4 * (g + 1) * (g + 2) <= rem) ++g;
    while (4 * g * (g + 1) > rem) --g;
    const int off = rem - 4 * g * (g + 1);
    const int nc = g + 1;
    const int qti = off / nc;
    const int kc = off - qti * nc;
    const int qt = g * 8 + qti;
    const int r0 = qt * 16;

    BF8 aq[2];
    {
        const unsigned short* qtile = qf + (size_t)(b * 128 + qt) * 1024;
        aq[0].u = *(const uint4*)(qtile + lane * 8);
        aq[1].u = *(const uint4*)(qtile + 512 + lane * 8);
    }

    floatx4 oacc[4];
#pragma unroll
    for (int nt = 0; nt < 4; ++nt) oacc[nt] = (floatx4)(0.0f);
    float m_i[4], l_i[4];
#pragma unroll
    for (int r = 0; r < 4; ++r) { m_i[r] = -3.0e38f; l_i[r] = 0.0f; }

    unsigned short* myp = lds_p + w * (16 * 72);

    for (int t = 0; t < 2; ++t) {
        const int j0 = kc * 128 + t * 64;
        if (j0 > r0 + 15) break;

        floatx4 s[4];
#pragma unroll
        for (int nt = 0; nt < 4; ++nt) s[nt] = (floatx4)(0.0f);
#pragma unroll
        for (int kst = 0; kst < 2; ++kst) {
#pragma unroll
            for (int nt = 0; nt < 4; ++nt) {
                BF8 bk;
                bk.u = *(const uint4*)(kf + (size_t)(b * 128 + (j0 >> 4) + nt) * 1024 +
                                       kst * 512 + lane * 8);
                s[nt] = __builtin_amdgcn_mfma_f32_16x16x32_bf16(aq[kst].v, bk.v, s[nt], 0, 0, 0);
            }
        }

        float sv[4][4];
        const bool masked = (j0 + 63 > r0);
#pragma unroll
        for (int nt = 0; nt < 4; ++nt)
#pragma unroll
            for (int r = 0; r < 4; ++r) {
                float val = s[nt][r] * 0.125f;
                if (masked) {
                    int key = j0 + nt * 16 + l16;
                    int qr = r0 + quad * 4 + r;
                    if (key > qr) val = -3.0e38f;
                }
                sv[nt][r] = val;
            }

        float alpha[4];
#pragma unroll
        for (int r = 0; r < 4; ++r) {
            float mx = fmaxf(fmaxf(sv[0][r], sv[1][r]), fmaxf(sv[2][r], sv[3][r]));
            mx = fmaxf(mx, __shfl_xor(mx, 1));
            mx = fmaxf(mx, __shfl_xor(mx, 2));
            mx = fmaxf(mx, __shfl_xor(mx, 4));
            mx = fmaxf(mx, __shfl_xor(mx, 8));
            float mn = fmaxf(m_i[r], mx);
            alpha[r] = __expf(m_i[r] - mn);
            m_i[r] = mn;
        }
        float rs[4] = {0.f, 0.f, 0.f, 0.f};
#pragma unroll
        for (int nt = 0; nt < 4; ++nt)
#pragma unroll
            for (int r = 0; r < 4; ++r) {
                float p = __expf(sv[nt][r] - m_i[r]);
                sv[nt][r] = p;
                rs[r] += p;
            }
#pragma unroll
        for (int r = 0; r < 4; ++r) {
            float t2 = rs[r];
            t2 += __shfl_xor(t2, 1);
            t2 += __shfl_xor(t2, 2);
            t2 += __shfl_xor(t2, 4);
            t2 += __shfl_xor(t2, 8);
            l_i[r] = l_i[r] * alpha[r] + t2;
        }
#pragma unroll
        for (int nt = 0; nt < 4; ++nt)
#pragma unroll
            for (int r = 0; r < 4; ++r) oacc[nt][r] *= alpha[r];

#pragma unroll
        for (int nt = 0; nt < 4; ++nt)
#pragma unroll
            for (int r = 0; r < 4; ++r)
                myp[(quad * 4 + r) * 72 + nt * 16 + l16] = f2bf(sv[nt][r]);

#pragma unroll
        for (int kst = 0; kst < 2; ++kst) {
            BF8 ap;
            ap.u = *(const uint4*)(myp + l16 * 72 + kst * 32 + quad * 8);
#pragma unroll
            for (int nt = 0; nt < 4; ++nt) {
                BF8 bv;
                bv.u = *(const uint4*)(vf + ((size_t)(b * 32 + (j0 >> 6)) * 4 + nt) * 1024 +
                                       kst * 512 + lane * 8);
                oacc[nt] = __builtin_amdgcn_mfma_f32_16x16x32_bf16(ap.v, bv.v, oacc[nt], 0, 0, 0);
            }
        }
    }

    const size_t ob = (size_t)gid * 1024;
#pragma unroll
    for (int nt = 0; nt < 4; ++nt)
#pragma unroll
        for (int r = 0; r < 4; ++r)
            Opart[ob + (quad * 4 + r) * 64 + nt * 16 + l16] = f2bf(oacc[nt][r]);
    if (l16 == 0) {
#pragma unroll
        for (int r = 0; r < 4; ++r) {
            mpart[gid * 16 + quad * 4 + r] = m_i[r];
            lpart[gid * 16 + quad * 4 + r] = l_i[r];
        }
    }
}

// ---------------------------------------------------------------------------
// Kernel 3: merge, flat online single pass. 2048 blocks; one thread per
// output element. Triangular base id per (b,qt); nc = (qt>>3)+1 <= 16.
// ---------------------------------------------------------------------------
__global__ __launch_bounds__(256) void attn_merge(const unsigned short* __restrict__ Opart,
                                                  const float* __restrict__ mpart,
                                                  const float* __restrict__ lpart,
                                                  float* __restrict__ out) {
    const int e = blockIdx.x * 256 + threadIdx.x;
    const int col = e & 63;
    const int t = (e >> 6) & 2047;
    const int b = e >> 17;
    const int qt = t >> 4;
    const int row16 = t & 15;
    const int g = qt >> 3;
    const int nc = g + 1;
    const int base_id = b * 1088 + 4 * g * (g + 1) + (qt & 7) * nc;

    float M = -3.0e38f, L = 0.0f, O = 0.0f;
#pragma unroll 4
    for (int c = 0; c < nc; ++c) {
        const float m_c = mpart[(base_id + c) * 16 + row16];
        const float l_c = lpart[(base_id + c) * 16 + row16];
        const float o_c = bf2f(Opart[(size_t)(base_id + c) * 1024 + row16 * 64 + col]);
        const float Mn = fmaxf(M, m_c);
        const float a = __expf(M - Mn);
        const float ec = __expf(m_c - Mn);
        L = L * a + ec * l_c;
        O = O * a + ec * o_c;
        M = Mn;
    }
    out[e] = O / L;
}

extern "C" void kernel_launch(void* const* d_in, const int* in_sizes, int n_in,
                              void* d_out, int out_size, void* d_ws, size_t ws_size,
                              hipStream_t stream) {
    const float* x = (const float*)d_in[0];
    const float* Wq = (const float*)d_in[1];
    const float* Wk = (const float*)d_in[2];
    const float* Wv = (const float*)d_in[3];
    float* out = (float*)d_out;

    char* ws = (char*)d_ws;
    unsigned short* wtf = (unsigned short*)(ws);
    unsigned short* qf = (unsigned short*)(ws + 393216);
    unsigned short* kf = (unsigned short*)(ws + 1441792);
    unsigned short* vf = (unsigned short*)(ws + 2490368);
    unsigned short* Opart = (unsigned short*)(ws + 3538944);
    float* mpart = (float*)(ws + 12451840ull);
    float* lpart = (float*)(ws + 12730368ull);

    hipLaunchKernelGGL(wt_kernel, dim3(48), dim3(256), 0, stream, Wq, Wk, Wv, wtf);
    hipLaunchKernelGGL(qkv_kernel, dim3(512), dim3(256), 0, stream, x, wtf, qf, kf, vf);
    hipLaunchKernelGGL(attn_partial, dim3(1088), dim3(256), 0, stream, qf, kf, vf, Opart, mpart, lpart);
    hipLaunchKernelGGL(attn_merge, dim3(2048), dim3(256), 0, stream, Opart, mpart, lpart, out);
}